// Round 9
// baseline (182.717 us; speedup 1.0000x reference)
//
#include <hip/hip_runtime.h>

// LSTM: B=8192 seqs, T=512, D=5, H=10, Linear(10,1) head.
// 16 lanes/seq (lane j<10 owns hidden unit j), 2048 waves = 2/SIMD.
// R9 (= R8 with compile fix): gate MACs via v_dot2_f32_f16 (full-rate 2-way
// f16 dot, f32 accumulate): 60 MACs/step = 32 fdot2 (64 exec cyc) vs 30
// pk_fma (120 cyc + ~15 splat movs). Inputs f16-quantized (5e-4 rel),
// accumulation stays f32. Keeps R5's 8-step register x double-buffer, DPP
// row_newbcast h-broadcast, exp2-domain pre-scaled weights, R6 fused
// single-rcp activation tail.
// Fix vs R8: cvt_pkrtz returns a __fp16 ext-vector; bit_cast it to the
// _Float16 ext-vector type that __builtin_amdgcn_fdot2 expects.

#define BATCH  8192
#define SEQLEN 512
#define INSZ   5
#define HID    10
#define BSTEP  8                 // steps per x block
#define BV     10                // f32x4 regs per block (BSTEP*INSZ/4)

#define L2E  1.442695040888963f   // log2(e)
#define L2E2 2.885390081777927f   // 2*log2(e)

typedef float f32x4 __attribute__((ext_vector_type(4)));
typedef _Float16 f16x2 __attribute__((ext_vector_type(2)));

// Broadcast lane K (0..15) of each 16-lane row to the whole row.
// v_mov_b32_dpp row_newbcast:K (ctrl 0x150+K, gfx90a+).
template<int K>
__device__ __forceinline__ float rowbcast(float v) {
    int r = __builtin_amdgcn_update_dpp(0, __builtin_bit_cast(int, v),
                                        0x150 + K, 0xF, 0xF, false);
    return __builtin_bit_cast(float, r);
}

__device__ __forceinline__ f16x2 pkcvt(float a, float b) {
    return __builtin_bit_cast(f16x2, __builtin_amdgcn_cvt_pkrtz(a, b));
}

#if __has_builtin(__builtin_amdgcn_fdot2)
__device__ __forceinline__ float fdot2(f16x2 a, f16x2 b, float c) {
    return __builtin_amdgcn_fdot2(a, b, c, false);
}
#else
__device__ __forceinline__ float fdot2(f16x2 a, f16x2 b, float c) {
    return fmaf((float)a.x, (float)b.x, fmaf((float)a.y, (float)b.y, c));
}
#endif

__global__ __launch_bounds__(256, 2) void lstm_fused(
    const float* __restrict__ x,     // [B, T, D]
    const float* __restrict__ Wih,   // [4H, D]
    const float* __restrict__ Whh,   // [4H, H]
    const float* __restrict__ bih,   // [4H]
    const float* __restrict__ bhh,   // [4H]
    const float* __restrict__ Wout,  // [1, H]
    const float* __restrict__ bout,  // [1]
    float* __restrict__ out)         // [B, 1]
{
    const int tid = blockIdx.x * blockDim.x + threadIdx.x;
    const int seq = tid >> 4;
    const int j   = tid & 15;
    const int ju  = (j < HID) ? j : 0;   // pad lanes duplicate unit 0 (never read)

    // Gate g of unit ju = row g*H+ju. Pre-scale so the accumulated gate value
    // is directly the exp2 argument: i,f,o: *-log2e (e^{-a}); g: *2log2e (e^{2a}).
    const float sc[4] = { -L2E, -L2E, L2E2, -L2E };

    f16x2 wihh[4][3];   // x-weight pairs {w0,w1},{w2,w3},{w4,0}, pre-scaled f16
    f16x2 whhh[4][5];   // h-weight pairs {w0,w1}..{w8,w9}, pre-scaled f16
    float bsc[4];       // pre-scaled bias (f32)
#pragma unroll
    for (int g = 0; g < 4; ++g) {
        const int row = g * HID + ju;
        const float s = sc[g];
        wihh[g][0] = pkcvt(s * Wih[row * INSZ + 0], s * Wih[row * INSZ + 1]);
        wihh[g][1] = pkcvt(s * Wih[row * INSZ + 2], s * Wih[row * INSZ + 3]);
        wihh[g][2] = pkcvt(s * Wih[row * INSZ + 4], 0.0f);
#pragma unroll
        for (int p = 0; p < 5; ++p)
            whhh[g][p] = pkcvt(s * Whh[row * HID + 2 * p], s * Whh[row * HID + 2 * p + 1]);
        bsc[g] = s * (bih[row] + bhh[row]);
    }

    const float* xp = x + (size_t)seq * SEQLEN * INSZ;
    float h = 0.0f;
    float cs = 0.0f;   // c' = 2*log2e * c  (exp2-ready cell state)

    f32x4 bufA[BV], bufB[BV];
    {
        const f32x4* v4 = reinterpret_cast<const f32x4*>(xp);
#pragma unroll
        for (int i = 0; i < BV; ++i) bufA[i] = v4[i];
    }

    // Fused step:
    //  A=e^{-a0} E1=e^{-a1} U=e^{2a2} B=e^{-a3}  (4 independent exp2)
    //  cs = [cs*(1+A)(1+U) + 2log2e*(U-1)*(1+E1)] * rcp((1+E1)(1+A)(1+U))
    //  V = exp2(cs);  h = (V-1) * rcp((1+B)(1+V))
#define DO_STEP(cx, s)                                                        \
    {                                                                         \
        /* x pairs for this sub-step (h-independent; fills DPP window) */     \
        const int ixb = (s) * INSZ;                                           \
        const float xv0 = cx[(ixb + 0) >> 2][(ixb + 0) & 3];                  \
        const float xv1 = cx[(ixb + 1) >> 2][(ixb + 1) & 3];                  \
        const float xv2 = cx[(ixb + 2) >> 2][(ixb + 2) & 3];                  \
        const float xv3 = cx[(ixb + 3) >> 2][(ixb + 3) & 3];                  \
        const float xv4 = cx[(ixb + 4) >> 2][(ixb + 4) & 3];                  \
        const f16x2 xp0 = pkcvt(xv0, xv1);                                    \
        const f16x2 xp1 = pkcvt(xv2, xv3);                                    \
        const f16x2 xp2 = pkcvt(xv4, 0.0f);                                   \
        float a0 = bsc[0], a1 = bsc[1], a2 = bsc[2], a3 = bsc[3];             \
        a0 = fdot2(xp0, wihh[0][0], a0); a1 = fdot2(xp0, wihh[1][0], a1);     \
        a2 = fdot2(xp0, wihh[2][0], a2); a3 = fdot2(xp0, wihh[3][0], a3);     \
        a0 = fdot2(xp1, wihh[0][1], a0); a1 = fdot2(xp1, wihh[1][1], a1);     \
        a2 = fdot2(xp1, wihh[2][1], a2); a3 = fdot2(xp1, wihh[3][1], a3);     \
        a0 = fdot2(xp2, wihh[0][2], a0); a1 = fdot2(xp2, wihh[1][2], a1);     \
        a2 = fdot2(xp2, wihh[2][2], a2); a3 = fdot2(xp2, wihh[3][2], a3);     \
        /* h broadcast (f32 DPP) + pack to f16 pairs */                       \
        const float hv0 = rowbcast<0>(h), hv1 = rowbcast<1>(h);               \
        const float hv2 = rowbcast<2>(h), hv3 = rowbcast<3>(h);               \
        const float hv4 = rowbcast<4>(h), hv5 = rowbcast<5>(h);               \
        const float hv6 = rowbcast<6>(h), hv7 = rowbcast<7>(h);               \
        const float hv8 = rowbcast<8>(h), hv9 = rowbcast<9>(h);               \
        const f16x2 hp0 = pkcvt(hv0, hv1);                                    \
        const f16x2 hp1 = pkcvt(hv2, hv3);                                    \
        const f16x2 hp2 = pkcvt(hv4, hv5);                                    \
        const f16x2 hp3 = pkcvt(hv6, hv7);                                    \
        const f16x2 hp4 = pkcvt(hv8, hv9);                                    \
        a0 = fdot2(hp0, whhh[0][0], a0); a1 = fdot2(hp0, whhh[1][0], a1);     \
        a2 = fdot2(hp0, whhh[2][0], a2); a3 = fdot2(hp0, whhh[3][0], a3);     \
        a0 = fdot2(hp1, whhh[0][1], a0); a1 = fdot2(hp1, whhh[1][1], a1);     \
        a2 = fdot2(hp1, whhh[2][1], a2); a3 = fdot2(hp1, whhh[3][1], a3);     \
        a0 = fdot2(hp2, whhh[0][2], a0); a1 = fdot2(hp2, whhh[1][2], a1);     \
        a2 = fdot2(hp2, whhh[2][2], a2); a3 = fdot2(hp2, whhh[3][2], a3);     \
        a0 = fdot2(hp3, whhh[0][3], a0); a1 = fdot2(hp3, whhh[1][3], a1);     \
        a2 = fdot2(hp3, whhh[2][3], a2); a3 = fdot2(hp3, whhh[3][3], a3);     \
        a0 = fdot2(hp4, whhh[0][4], a0); a1 = fdot2(hp4, whhh[1][4], a1);     \
        a2 = fdot2(hp4, whhh[2][4], a2); a3 = fdot2(hp4, whhh[3][4], a3);     \
        /* fused single-rcp activation tail (f32) */                          \
        const float A  = __builtin_amdgcn_exp2f(a0);                          \
        const float E1 = __builtin_amdgcn_exp2f(a1);                          \
        const float U  = __builtin_amdgcn_exp2f(a2);                          \
        const float Bo = __builtin_amdgcn_exp2f(a3);                          \
        const float t1 = 1.0f + A;                                            \
        const float t2 = 1.0f + E1;                                           \
        const float t3 = 1.0f + U;                                            \
        const float um = fmaf(L2E2, U, -L2E2);   /* 2log2e*(U-1) */           \
        const float m1 = t1 * t3;                                             \
        const float d1 = t2 * m1;                                             \
        const float r1v = __builtin_amdgcn_rcpf(d1);                          \
        const float num = fmaf(cs, m1, um * t2);                              \
        cs = num * r1v;                                                       \
        const float V = __builtin_amdgcn_exp2f(cs);                           \
        const float t4 = 1.0f + Bo;                                           \
        const float t5 = 1.0f + V;                                            \
        const float d2 = t4 * t5;                                             \
        const float r2v = __builtin_amdgcn_rcpf(d2);                          \
        h = (V - 1.0f) * r2v;                                                 \
    }

    // 32 iterations x 2 phases of 8 steps; A/B role swap (no copies).
    for (int it = 0; it < SEQLEN / (2 * BSTEP); ++it) {
        const int tb = it * 2 * BSTEP;
        // phase A: prefetch next block into B, compute 8 steps from A
        {
            const f32x4* v4 = reinterpret_cast<const f32x4*>(xp + (tb + BSTEP) * INSZ);
#pragma unroll
            for (int i = 0; i < BV; ++i) bufB[i] = v4[i];
#pragma unroll
            for (int s = 0; s < BSTEP; ++s) DO_STEP(bufA, s)
        }
        // phase B: prefetch block tb+2 into A (clamped on last iter), compute from B
        {
            int nb = tb + 2 * BSTEP;
            if (nb > SEQLEN - BSTEP) nb = SEQLEN - BSTEP;   // harmless reload
            const f32x4* v4 = reinterpret_cast<const f32x4*>(xp + nb * INSZ);
#pragma unroll
            for (int i = 0; i < BV; ++i) bufA[i] = v4[i];
#pragma unroll
            for (int s = 0; s < BSTEP; ++s) DO_STEP(bufB, s)
        }
    }
#undef DO_STEP

    // head: out[seq] = sum_j Wout[j]*h_j + bout
    float p = (j < HID) ? Wout[ju] * h : 0.0f;
    p += __shfl_xor(p, 8, 16);
    p += __shfl_xor(p, 4, 16);
    p += __shfl_xor(p, 2, 16);
    p += __shfl_xor(p, 1, 16);
    if (j == 0) out[seq] = p + bout[0];
}

extern "C" void kernel_launch(void* const* d_in, const int* in_sizes, int n_in,
                              void* d_out, int out_size, void* d_ws, size_t ws_size,
                              hipStream_t stream) {
    const float* x    = (const float*)d_in[0];
    const float* Wih  = (const float*)d_in[1];
    const float* Whh  = (const float*)d_in[2];
    const float* bih  = (const float*)d_in[3];
    const float* bhh  = (const float*)d_in[4];
    const float* Wout = (const float*)d_in[5];
    const float* bout = (const float*)d_in[6];
    float* out = (float*)d_out;

    const int threads = 256;
    const int blocks  = (BATCH * 16) / threads;  // 512
    lstm_fused<<<blocks, threads, 0, stream>>>(x, Wih, Whh, bih, bhh, Wout, bout, out);
}

// Round 10
// 138.661 us; speedup vs baseline: 1.3177x; 1.3177x over previous
//
#include <hip/hip_runtime.h>

// LSTM: B=8192 seqs, T=512, D=5, H=10, Linear(10,1) head.
// R10: MFMA restructure. Wave = 4 seqs (2048 waves = 2/SIMD, same TLP as R7).
// Per step, gates[40 rows x 4 seqs] are computed as ONE 16x16 output tile:
// col = 4*seq + chunk(q), with 3 chained v_mfma_f32_16x16x16_f16 over
// K=16 state slots [x0..x4, 1(bias), h0..h9]; chunk p's B operand is the
// state masked by (q==p), A_p = W'[16p..16p+15] (rows packed i,f,g,o per
// unit, exp2-domain pre-scaled, f16). C/D layout => lane l holds exactly
// the 4 gates of unit u=4q+g (g=l>>4) of seq s=(l&15)>>2 -> one fused
// activation per lane (R6 single-rcp tail). h exchanged through a 96B/wave
// LDS buffer (1 ds_write_b16 + 2 ds_read_b32 per lane, addrs precomputed).
// Keeps R5/R7's 8-step register x double-buffer.

#define BATCH  8192
#define SEQLEN 512
#define INSZ   5
#define HID    10
#define BSTEP  8                 // steps per x block
#define BV     10                // f32x4 regs per block (BSTEP*INSZ/4)

#define L2E  1.442695040888963f   // log2(e)
#define L2E2 2.885390081777927f   // 2*log2(e)

typedef float     f32x4 __attribute__((ext_vector_type(4)));
typedef _Float16  f16x4 __attribute__((ext_vector_type(4)));
typedef unsigned  u32x2 __attribute__((ext_vector_type(2)));

__device__ __forceinline__ unsigned pkh(float a, float b) {
    return __builtin_bit_cast(unsigned, __builtin_amdgcn_cvt_pkrtz(a, b));
}
__device__ __forceinline__ f16x4 mkab(unsigned lo, unsigned hi) {
    u32x2 t; t.x = lo; t.y = hi;
    return __builtin_bit_cast(f16x4, t);
}
__device__ __forceinline__ f32x4 mfma16(f16x4 a, f16x4 b, f32x4 c) {
    return __builtin_amdgcn_mfma_f32_16x16x16f16(a, b, c, 0, 0, 0);
}

__global__ __launch_bounds__(256, 2) void lstm_mfma(
    const float* __restrict__ x,     // [B, T, D]
    const float* __restrict__ Wih,   // [4H, D]
    const float* __restrict__ Whh,   // [4H, H]
    const float* __restrict__ bih,   // [4H]
    const float* __restrict__ bhh,   // [4H]
    const float* __restrict__ Wout,  // [1, H]
    const float* __restrict__ bout,  // [1]
    float* __restrict__ out)         // [B, 1]
{
    const int lane  = threadIdx.x & 63;
    const int wid   = threadIdx.x >> 6;
    const int gwave = (blockIdx.x * blockDim.x + threadIdx.x) >> 6;
    const int col   = lane & 15;     // output tile column = 4*sq + q
    const int g     = lane >> 4;     // k-group / row-group
    const int q     = col & 3;       // chunk selector
    const int sq    = col >> 2;      // seq within wave (0..3)
    const size_t seq = (size_t)gwave * 4 + sq;

    __shared__ unsigned short hsh[4][48];   // per wave: 4 seqs x 10 h (f16) + dump

    if (lane < 48) hsh[wid][lane] = 0;      // h(0) = 0

    // ---- A fragments: W' rows (packed i,f,g,o per unit), f16, pre-scaled ----
    // W' cols: j<5 -> Wih[.][j]; j==5 -> bih+bhh; j>=6 -> Whh[.][j-6].
    f16x4 Af[3];
#pragma unroll
    for (int p = 0; p < 3; ++p) {
        const int rr = 16 * p + col;            // W' row 0..47 (40+ = pad)
        const int rc = (rr < 40) ? rr : 0;
        const int uu = rc >> 2, gate = rc & 3;
        const int orow = gate * HID + uu;       // row in original [4H] layout
        const float sg = (gate == 2) ? L2E2 : -L2E;
        f16x4 a;
#pragma unroll
        for (int e = 0; e < 4; ++e) {
            const int jj = 4 * g + e;           // k slot
            float w;
            if (jj < 5)       w = Wih[orow * INSZ + jj];
            else if (jj == 5) w = bih[orow] + bhh[orow];
            else              w = Whh[orow * HID + (jj - 6)];
            if (rr >= 40) w = 0.0f;
            a[e] = (_Float16)(sg * w);
        }
        Af[p] = a;
    }

    // ---- per-lane constant LDS addresses ----
    const int base = sq * 10;
    const int u    = 4 * q + g;                 // unit this lane activates
    const int widx = (u < HID) ? (base + u) : (40 + (lane & 7));  // pads -> dump
    volatile unsigned short* wp = &hsh[wid][widx];
    // B-slice pairs this lane must read (even indices -> 4B aligned):
    //  pairA (k 4g,4g+1):  g2 -> h2h3(+2), g3 -> h6h7(+6)
    //  pairB (k 4g+2,+3):  g1 -> h0h1(+0), g2 -> h4h5(+4), g3 -> h8h9(+8)
    const int raidx = (g == 2) ? base + 2 : (g == 3) ? base + 6 : base;
    const int rbidx = (g == 1) ? base : (g == 2) ? base + 4 : (g == 3) ? base + 8 : base;
    volatile const unsigned* pA = (volatile const unsigned*)&hsh[wid][raidx];
    volatile const unsigned* pB = (volatile const unsigned*)&hsh[wid][rbidx];

    const bool isG0 = (g == 0), isG1 = (g == 1);
    const bool isQ0 = (q == 0), isQ1 = (q == 1), isQ2 = (q == 2);

    const float* xp = x + seq * SEQLEN * INSZ;
    float cs = 0.0f;   // cell state (exp2-scaled) of unit u, seq sq

    f32x4 bufA[BV], bufB[BV];
    {
        const f32x4* v4 = (const f32x4*)xp;
#pragma unroll
        for (int i = 0; i < BV; ++i) bufA[i] = v4[i];
    }
    asm volatile("s_waitcnt lgkmcnt(0)" ::: "memory");  // h=0 init visible

#define DO_STEP(cx, ss)                                                      \
    {                                                                        \
        const unsigned rA = *pA;                                             \
        const unsigned rB = *pB;                                             \
        const int ixb = (ss) * INSZ;                                         \
        const float xv0 = cx[(ixb + 0) >> 2][(ixb + 0) & 3];                 \
        const float xv1 = cx[(ixb + 1) >> 2][(ixb + 1) & 3];                 \
        const float xv2 = cx[(ixb + 2) >> 2][(ixb + 2) & 3];                 \
        const float xv3 = cx[(ixb + 3) >> 2][(ixb + 3) & 3];                 \
        const float xv4 = cx[(ixb + 4) >> 2][(ixb + 4) & 3];                 \
        const unsigned cA0 = pkh(xv0, xv1);   /* g0 pairA: x0,x1 */          \
        const unsigned cA1 = pkh(xv4, 1.0f);  /* g1 pairA: x4,1  */          \
        const unsigned cB0 = pkh(xv2, xv3);   /* g0 pairB: x2,x3 */          \
        const unsigned pairA = isG0 ? cA0 : (isG1 ? cA1 : rA);               \
        const unsigned pairB = isG0 ? cB0 : rB;                              \
        const f16x4 B0 = mkab(isQ0 ? pairA : 0u, isQ0 ? pairB : 0u);         \
        const f16x4 B1 = mkab(isQ1 ? pairA : 0u, isQ1 ? pairB : 0u);         \
        const f16x4 B2 = mkab(isQ2 ? pairA : 0u, isQ2 ? pairB : 0u);         \
        f32x4 acc = {0.f, 0.f, 0.f, 0.f};                                    \
        acc = mfma16(Af[0], B0, acc);                                        \
        acc = mfma16(Af[1], B1, acc);                                        \
        acc = mfma16(Af[2], B2, acc);                                        \
        const float A_  = __builtin_amdgcn_exp2f(acc[0]);                    \
        const float E1_ = __builtin_amdgcn_exp2f(acc[1]);                    \
        const float U_  = __builtin_amdgcn_exp2f(acc[2]);                    \
        const float Bo_ = __builtin_amdgcn_exp2f(acc[3]);                    \
        const float t1 = 1.0f + A_;                                          \
        const float t2 = 1.0f + E1_;                                         \
        const float t3 = 1.0f + U_;                                          \
        const float um = fmaf(L2E2, U_, -L2E2);  /* 2log2e*(U-1) */          \
        const float m1 = t1 * t3;                                            \
        const float d1 = t2 * m1;                                            \
        const float r1v = __builtin_amdgcn_rcpf(d1);                         \
        const float num = fmaf(cs, m1, um * t2);                             \
        cs = num * r1v;                                                      \
        const float V = __builtin_amdgcn_exp2f(cs);                          \
        const float t4 = 1.0f + Bo_;                                         \
        const float t5 = 1.0f + V;                                           \
        const float r2v = __builtin_amdgcn_rcpf(t4 * t5);                    \
        const float h = (V - 1.0f) * r2v;                                    \
        *wp = __builtin_bit_cast(unsigned short, (_Float16)h);               \
        asm volatile("s_waitcnt lgkmcnt(0)" ::: "memory");                   \
    }

    // 32 iterations x 2 phases of 8 steps; x buffer role swap (no copies).
    for (int it = 0; it < SEQLEN / (2 * BSTEP); ++it) {
        const int tb = it * 2 * BSTEP;
        {
            const f32x4* v4 = (const f32x4*)(xp + (tb + BSTEP) * INSZ);
#pragma unroll
            for (int i = 0; i < BV; ++i) bufB[i] = v4[i];
#pragma unroll
            for (int ss = 0; ss < BSTEP; ++ss) DO_STEP(bufA, ss)
        }
        {
            int nb = tb + 2 * BSTEP;
            if (nb > SEQLEN - BSTEP) nb = SEQLEN - BSTEP;   // harmless reload
            const f32x4* v4 = (const f32x4*)(xp + nb * INSZ);
#pragma unroll
            for (int i = 0; i < BV; ++i) bufA[i] = v4[i];
#pragma unroll
            for (int ss = 0; ss < BSTEP; ++ss) DO_STEP(bufB, ss)
        }
    }
#undef DO_STEP

    // head: out[seq] = sum_u Wout[u]*h_u + bout ; final h sits in LDS (f16)
    if (g == 0 && q == 0) {      // lanes 0,4,8,12 -> seqs sq=0..3
        float r = bout[0];
#pragma unroll
        for (int uu = 0; uu < HID; ++uu) {
            const float hv = (float)__builtin_bit_cast(_Float16, hsh[wid][base + uu]);
            r = fmaf(Wout[uu], hv, r);
        }
        out[gwave * 4 + sq] = r;
    }
}

extern "C" void kernel_launch(void* const* d_in, const int* in_sizes, int n_in,
                              void* d_out, int out_size, void* d_ws, size_t ws_size,
                              hipStream_t stream) {
    const float* x    = (const float*)d_in[0];
    const float* Wih  = (const float*)d_in[1];
    const float* Whh  = (const float*)d_in[2];
    const float* bih  = (const float*)d_in[3];
    const float* bhh  = (const float*)d_in[4];
    const float* Wout = (const float*)d_in[5];
    const float* bout = (const float*)d_in[6];
    float* out = (float*)d_out;

    const int threads = 256;
    const int blocks  = (BATCH * 16) / threads;  // 512 blocks = 2048 waves
    lstm_mfma<<<blocks, threads, 0, stream>>>(x, Wih, Whh, bih, bhh, Wout, bout, out);
}

// Round 12
// 130.446 us; speedup vs baseline: 1.4007x; 1.0630x over previous
//
#include <hip/hip_runtime.h>

// LSTM: B=8192 seqs, T=512, D=5, H=10, Linear(10,1) head.
// R12 (= R11 + missing 4th chunk): wave = 4 seqs, 2048 waves = 2/SIMD.
// Unit map u = 4g+q-6 spans quad positions q=0..3, so W' is padded to 64
// rows = FOUR 16-row chunks; R11 computed only 3 -> units 1,5,9 (q=3) had
// acc=0 and h==0 (absmax 0.109). Chunk 3 holds exactly those units.
// Per step: 4 independent masked-B mfma_f32_16x16x16_f16 (disjoint cols,
// separate accumulators, summed pairwise), h exchanged with 4 quad_perm
// DPP broadcasts (no LDS roundtrip), R6 fused single-rcp activation tail,
// 8-step register x double-buffer. LDS only for the final head reduction.

#define BATCH  8192
#define SEQLEN 512
#define INSZ   5
#define HID    10
#define BSTEP  8                 // steps per x block
#define BV     10                // f32x4 regs per block (BSTEP*INSZ/4)

#define L2E  1.442695040888963f   // log2(e)
#define L2E2 2.885390081777927f   // 2*log2(e)

typedef float     f32x4 __attribute__((ext_vector_type(4)));
typedef _Float16  f16x4 __attribute__((ext_vector_type(4)));
typedef unsigned  u32x2 __attribute__((ext_vector_type(2)));

__device__ __forceinline__ unsigned pkh(float a, float b) {
    return __builtin_bit_cast(unsigned, __builtin_amdgcn_cvt_pkrtz(a, b));
}
__device__ __forceinline__ f16x4 mkab(unsigned lo, unsigned hi) {
    u32x2 t; t.x = lo; t.y = hi;
    return __builtin_bit_cast(f16x4, t);
}
__device__ __forceinline__ f32x4 mfma16(f16x4 a, f16x4 b, f32x4 c) {
    return __builtin_amdgcn_mfma_f32_16x16x16f16(a, b, c, 0, 0, 0);
}
// Broadcast quad lane Q (0..3) to all 4 lanes of each quad (quad_perm DPP).
template<int Q>
__device__ __forceinline__ float quadbcast(float v) {
    int r = __builtin_amdgcn_update_dpp(0, __builtin_bit_cast(int, v),
                                        Q * 0x55, 0xF, 0xF, false);
    return __builtin_bit_cast(float, r);
}

__global__ __launch_bounds__(256, 2) void lstm_mfma(
    const float* __restrict__ x,     // [B, T, D]
    const float* __restrict__ Wih,   // [4H, D]
    const float* __restrict__ Whh,   // [4H, H]
    const float* __restrict__ bih,   // [4H]
    const float* __restrict__ bhh,   // [4H]
    const float* __restrict__ Wout,  // [1, H]
    const float* __restrict__ bout,  // [1]
    float* __restrict__ out)         // [B, 1]
{
    const int lane  = threadIdx.x & 63;
    const int wid   = threadIdx.x >> 6;
    const int gwave = (blockIdx.x * blockDim.x + threadIdx.x) >> 6;
    const int col   = lane & 15;     // output tile column = 4*sq + q
    const int g     = lane >> 4;     // k/row group
    const int q     = col & 3;       // quad position = chunk selector
    const int sq    = col >> 2;      // seq within wave (0..3)
    const size_t seq = (size_t)gwave * 4 + sq;

    __shared__ unsigned short hsh[4][48];   // final-h exchange only

    // Unit computed by this lane: u = 4g+q-6 (slot-aligned; <0 => pad).
    const int u = 4 * g + q - 6;
    const bool uvalid = (u >= 0) && (u < HID);

    // ---- A fragments (4 chunks) ----
    // Chunk p, row r (= constructing lane's col): unit 4*(r>>2)+p-6, gate r&3.
    // k-slot j: j<5 -> Wih[:,j]; j==5 -> bias; j>=6 -> Whh[:,j-6].
    // Pre-scale: gate 2 (g-gate) by +2log2e, others by -log2e (exp2 domain).
    f16x4 Af[4];
#pragma unroll
    for (int p = 0; p < 4; ++p) {
        const int ug   = 4 * (col >> 2) + p - 6;
        const int gate = col & 3;
        const bool v   = (ug >= 0) && (ug < HID);
        const int uc   = v ? ug : 0;
        const int orow = gate * HID + uc;
        const float sg = (gate == 2) ? L2E2 : -L2E;
        f16x4 a;
#pragma unroll
        for (int e = 0; e < 4; ++e) {
            const int jj = 4 * g + e;           // k slot
            float w;
            if (jj < 5)       w = Wih[orow * INSZ + jj];
            else if (jj == 5) w = bih[orow] + bhh[orow];
            else              w = Whh[orow * HID + (jj - 6)];
            a[e] = (_Float16)(v ? sg * w : 0.0f);
        }
        Af[p] = a;
    }

    const bool isG0 = (g == 0), isG1 = (g == 1);
    const bool isQ0 = (q == 0), isQ1 = (q == 1), isQ2 = (q == 2), isQ3 = (q == 3);

    const float* xp = x + seq * SEQLEN * INSZ;
    float h  = 0.0f;
    float cs = 0.0f;   // exp2-scaled cell state of unit u, seq sq

    f32x4 bufA[BV], bufB[BV];
    {
        const f32x4* v4 = (const f32x4*)xp;
#pragma unroll
        for (int i = 0; i < BV; ++i) bufA[i] = v4[i];
    }

#define DO_STEP(cx, ss)                                                      \
    {                                                                        \
        const int ixb = (ss) * INSZ;                                         \
        const float xv0 = cx[(ixb + 0) >> 2][(ixb + 0) & 3];                 \
        const float xv1 = cx[(ixb + 1) >> 2][(ixb + 1) & 3];                 \
        const float xv2 = cx[(ixb + 2) >> 2][(ixb + 2) & 3];                 \
        const float xv3 = cx[(ixb + 3) >> 2][(ixb + 3) & 3];                 \
        const float xv4 = cx[(ixb + 4) >> 2][(ixb + 4) & 3];                 \
        /* h values for my k-slots 4g+{0..3}: quad broadcasts (DPP) */       \
        const float b0 = quadbcast<0>(h), b1 = quadbcast<1>(h);              \
        const float b2 = quadbcast<2>(h), b3 = quadbcast<3>(h);              \
        const unsigned hA = pkh(b0, b1), hB = pkh(b2, b3);                   \
        const unsigned pairA = isG0 ? pkh(xv0, xv1)                          \
                             : (isG1 ? pkh(xv4, 1.0f) : hA);                 \
        const unsigned pairB = isG0 ? pkh(xv2, xv3) : hB;                    \
        const f16x4 B0 = mkab(isQ0 ? pairA : 0u, isQ0 ? pairB : 0u);         \
        const f16x4 B1 = mkab(isQ1 ? pairA : 0u, isQ1 ? pairB : 0u);         \
        const f16x4 B2 = mkab(isQ2 ? pairA : 0u, isQ2 ? pairB : 0u);         \
        const f16x4 B3 = mkab(isQ3 ? pairA : 0u, isQ3 ? pairB : 0u);         \
        f32x4 ac0 = {0.f, 0.f, 0.f, 0.f};                                    \
        f32x4 ac1 = {0.f, 0.f, 0.f, 0.f};                                    \
        f32x4 ac2 = {0.f, 0.f, 0.f, 0.f};                                    \
        f32x4 ac3 = {0.f, 0.f, 0.f, 0.f};                                    \
        ac0 = mfma16(Af[0], B0, ac0);                                        \
        ac1 = mfma16(Af[1], B1, ac1);                                        \
        ac2 = mfma16(Af[2], B2, ac2);                                        \
        ac3 = mfma16(Af[3], B3, ac3);                                        \
        const f32x4 acc = (ac0 + ac1) + (ac2 + ac3);                         \
        const float A_  = __builtin_amdgcn_exp2f(acc[0]);                    \
        const float E1_ = __builtin_amdgcn_exp2f(acc[1]);                    \
        const float U_  = __builtin_amdgcn_exp2f(acc[2]);                    \
        const float Bo_ = __builtin_amdgcn_exp2f(acc[3]);                    \
        const float t1 = 1.0f + A_;                                          \
        const float t2 = 1.0f + E1_;                                         \
        const float t3 = 1.0f + U_;                                          \
        const float um = fmaf(L2E2, U_, -L2E2);  /* 2log2e*(U-1) */          \
        const float m1 = t1 * t3;                                            \
        const float d1 = t2 * m1;                                            \
        const float r1v = __builtin_amdgcn_rcpf(d1);                         \
        const float num = fmaf(cs, m1, um * t2);                             \
        cs = num * r1v;                                                      \
        const float V = __builtin_amdgcn_exp2f(cs);                          \
        const float t4 = 1.0f + Bo_;                                         \
        const float t5 = 1.0f + V;                                           \
        const float r2v = __builtin_amdgcn_rcpf(t4 * t5);                    \
        h = (V - 1.0f) * r2v;                                                \
    }

    // 32 iterations x 2 phases of 8 steps; x buffer role swap (no copies).
    for (int it = 0; it < SEQLEN / (2 * BSTEP); ++it) {
        const int tb = it * 2 * BSTEP;
        {
            const f32x4* v4 = (const f32x4*)(xp + (tb + BSTEP) * INSZ);
#pragma unroll
            for (int i = 0; i < BV; ++i) bufB[i] = v4[i];
#pragma unroll
            for (int ss = 0; ss < BSTEP; ++ss) DO_STEP(bufA, ss)
        }
        {
            int nb = tb + 2 * BSTEP;
            if (nb > SEQLEN - BSTEP) nb = SEQLEN - BSTEP;   // harmless reload
            const f32x4* v4 = (const f32x4*)(xp + nb * INSZ);
#pragma unroll
            for (int i = 0; i < BV; ++i) bufA[i] = v4[i];
#pragma unroll
            for (int ss = 0; ss < BSTEP; ++ss) DO_STEP(bufB, ss)
        }
    }
#undef DO_STEP

    // head: out[seq] = sum_u Wout[u]*h_u + bout (one LDS exchange, per wave)
    const int base = sq * 10;
    const int widx = uvalid ? (base + u) : (40 + (lane & 7));
    hsh[wid][widx] = __builtin_bit_cast(unsigned short, (_Float16)h);
    asm volatile("s_waitcnt lgkmcnt(0)" ::: "memory");
    if (g == 0 && q == 0) {      // lanes 0,4,8,12 -> seqs sq=0..3
        float r = bout[0];
#pragma unroll
        for (int uu = 0; uu < HID; ++uu) {
            const float hv = (float)__builtin_bit_cast(_Float16, hsh[wid][base + uu]);
            r = fmaf(Wout[uu], hv, r);
        }
        out[gwave * 4 + sq] = r;
    }
}

extern "C" void kernel_launch(void* const* d_in, const int* in_sizes, int n_in,
                              void* d_out, int out_size, void* d_ws, size_t ws_size,
                              hipStream_t stream) {
    const float* x    = (const float*)d_in[0];
    const float* Wih  = (const float*)d_in[1];
    const float* Whh  = (const float*)d_in[2];
    const float* bih  = (const float*)d_in[3];
    const float* bhh  = (const float*)d_in[4];
    const float* Wout = (const float*)d_in[5];
    const float* bout = (const float*)d_in[6];
    float* out = (float*)d_out;

    const int threads = 256;
    const int blocks  = (BATCH * 16) / threads;  // 512 blocks = 2048 waves
    lstm_mfma<<<blocks, threads, 0, stream>>>(x, Wih, Whh, bih, bhh, Wout, bout, out);
}

// Round 13
// 124.085 us; speedup vs baseline: 1.4725x; 1.0513x over previous
//
#include <hip/hip_runtime.h>

// LSTM: B=8192 seqs, T=512, D=5, H=10, Linear(10,1) head.
// R13 (= R12 + chained MFMA pairs): wave = 4 seqs, 2048 waves = 2/SIMD.
// The 4 chunk-MFMAs have disjoint masked columns, so they chain exactly:
// ac01 = mfma(A1,B1, mfma(A0,B0,0)), ac23 = mfma(A3,B3, mfma(A2,B2,0)),
// acc = ac01+ac23 — saves 8 v_add + 8 zero-inits vs 4 separate accs while
// keeping two parallel dependency chains. Everything else = R12: quad_perm
// DPP h-exchange (u = 4g+q-6 slot-aligned), exp2-domain pre-scaled f16
// weights, R6 fused single-rcp activation tail, 8-step register x
// double-buffer. LDS only for the final head reduction.

#define BATCH  8192
#define SEQLEN 512
#define INSZ   5
#define HID    10
#define BSTEP  8                 // steps per x block
#define BV     10                // f32x4 regs per block (BSTEP*INSZ/4)

#define L2E  1.442695040888963f   // log2(e)
#define L2E2 2.885390081777927f   // 2*log2(e)

typedef float     f32x4 __attribute__((ext_vector_type(4)));
typedef _Float16  f16x4 __attribute__((ext_vector_type(4)));
typedef unsigned  u32x2 __attribute__((ext_vector_type(2)));

__device__ __forceinline__ unsigned pkh(float a, float b) {
    return __builtin_bit_cast(unsigned, __builtin_amdgcn_cvt_pkrtz(a, b));
}
__device__ __forceinline__ f16x4 mkab(unsigned lo, unsigned hi) {
    u32x2 t; t.x = lo; t.y = hi;
    return __builtin_bit_cast(f16x4, t);
}
__device__ __forceinline__ f32x4 mfma16(f16x4 a, f16x4 b, f32x4 c) {
    return __builtin_amdgcn_mfma_f32_16x16x16f16(a, b, c, 0, 0, 0);
}
// Broadcast quad lane Q (0..3) to all 4 lanes of each quad (quad_perm DPP).
template<int Q>
__device__ __forceinline__ float quadbcast(float v) {
    int r = __builtin_amdgcn_update_dpp(0, __builtin_bit_cast(int, v),
                                        Q * 0x55, 0xF, 0xF, false);
    return __builtin_bit_cast(float, r);
}

__global__ __launch_bounds__(256, 2) void lstm_mfma(
    const float* __restrict__ x,     // [B, T, D]
    const float* __restrict__ Wih,   // [4H, D]
    const float* __restrict__ Whh,   // [4H, H]
    const float* __restrict__ bih,   // [4H]
    const float* __restrict__ bhh,   // [4H]
    const float* __restrict__ Wout,  // [1, H]
    const float* __restrict__ bout,  // [1]
    float* __restrict__ out)         // [B, 1]
{
    const int lane  = threadIdx.x & 63;
    const int wid   = threadIdx.x >> 6;
    const int gwave = (blockIdx.x * blockDim.x + threadIdx.x) >> 6;
    const int col   = lane & 15;     // output tile column = 4*sq + q
    const int g     = lane >> 4;     // k/row group
    const int q     = col & 3;       // quad position = chunk selector
    const int sq    = col >> 2;      // seq within wave (0..3)
    const size_t seq = (size_t)gwave * 4 + sq;

    __shared__ unsigned short hsh[4][48];   // final-h exchange only

    // Unit computed by this lane: u = 4g+q-6 (slot-aligned; <0 => pad).
    const int u = 4 * g + q - 6;
    const bool uvalid = (u >= 0) && (u < HID);

    // ---- A fragments (4 chunks) ----
    // Chunk p, row r (= constructing lane's col): unit 4*(r>>2)+p-6, gate r&3.
    // k-slot j: j<5 -> Wih[:,j]; j==5 -> bias; j>=6 -> Whh[:,j-6].
    // Pre-scale: gate 2 (g-gate) by +2log2e, others by -log2e (exp2 domain).
    f16x4 Af[4];
#pragma unroll
    for (int p = 0; p < 4; ++p) {
        const int ug   = 4 * (col >> 2) + p - 6;
        const int gate = col & 3;
        const bool v   = (ug >= 0) && (ug < HID);
        const int uc   = v ? ug : 0;
        const int orow = gate * HID + uc;
        const float sg = (gate == 2) ? L2E2 : -L2E;
        f16x4 a;
#pragma unroll
        for (int e = 0; e < 4; ++e) {
            const int jj = 4 * g + e;           // k slot
            float w;
            if (jj < 5)       w = Wih[orow * INSZ + jj];
            else if (jj == 5) w = bih[orow] + bhh[orow];
            else              w = Whh[orow * HID + (jj - 6)];
            a[e] = (_Float16)(v ? sg * w : 0.0f);
        }
        Af[p] = a;
    }

    const bool isG0 = (g == 0), isG1 = (g == 1);
    const bool isQ0 = (q == 0), isQ1 = (q == 1), isQ2 = (q == 2), isQ3 = (q == 3);

    const float* xp = x + seq * SEQLEN * INSZ;
    float h  = 0.0f;
    float cs = 0.0f;   // exp2-scaled cell state of unit u, seq sq

    f32x4 bufA[BV], bufB[BV];
    {
        const f32x4* v4 = (const f32x4*)xp;
#pragma unroll
        for (int i = 0; i < BV; ++i) bufA[i] = v4[i];
    }

#define DO_STEP(cx, ss)                                                      \
    {                                                                        \
        const int ixb = (ss) * INSZ;                                         \
        const float xv0 = cx[(ixb + 0) >> 2][(ixb + 0) & 3];                 \
        const float xv1 = cx[(ixb + 1) >> 2][(ixb + 1) & 3];                 \
        const float xv2 = cx[(ixb + 2) >> 2][(ixb + 2) & 3];                 \
        const float xv3 = cx[(ixb + 3) >> 2][(ixb + 3) & 3];                 \
        const float xv4 = cx[(ixb + 4) >> 2][(ixb + 4) & 3];                 \
        /* h values for my k-slots 4g+{0..3}: quad broadcasts (DPP) */       \
        const float b0 = quadbcast<0>(h), b1 = quadbcast<1>(h);              \
        const float b2 = quadbcast<2>(h), b3 = quadbcast<3>(h);              \
        const unsigned hA = pkh(b0, b1), hB = pkh(b2, b3);                   \
        const unsigned pairA = isG0 ? pkh(xv0, xv1)                          \
                             : (isG1 ? pkh(xv4, 1.0f) : hA);                 \
        const unsigned pairB = isG0 ? pkh(xv2, xv3) : hB;                    \
        const f16x4 B0 = mkab(isQ0 ? pairA : 0u, isQ0 ? pairB : 0u);         \
        const f16x4 B1 = mkab(isQ1 ? pairA : 0u, isQ1 ? pairB : 0u);         \
        const f16x4 B2 = mkab(isQ2 ? pairA : 0u, isQ2 ? pairB : 0u);         \
        const f16x4 B3 = mkab(isQ3 ? pairA : 0u, isQ3 ? pairB : 0u);         \
        const f32x4 zz = {0.f, 0.f, 0.f, 0.f};                               \
        f32x4 t01 = mfma16(Af[0], B0, zz);                                   \
        t01 = mfma16(Af[1], B1, t01);                                        \
        f32x4 t23 = mfma16(Af[2], B2, zz);                                   \
        t23 = mfma16(Af[3], B3, t23);                                        \
        const f32x4 acc = t01 + t23;                                         \
        const float A_  = __builtin_amdgcn_exp2f(acc[0]);                    \
        const float E1_ = __builtin_amdgcn_exp2f(acc[1]);                    \
        const float U_  = __builtin_amdgcn_exp2f(acc[2]);                    \
        const float Bo_ = __builtin_amdgcn_exp2f(acc[3]);                    \
        const float t1 = 1.0f + A_;                                          \
        const float t2 = 1.0f + E1_;                                         \
        const float t3 = 1.0f + U_;                                          \
        const float um = fmaf(L2E2, U_, -L2E2);  /* 2log2e*(U-1) */          \
        const float m1 = t1 * t3;                                            \
        const float d1 = t2 * m1;                                            \
        const float r1v = __builtin_amdgcn_rcpf(d1);                         \
        const float num = fmaf(cs, m1, um * t2);                             \
        cs = num * r1v;                                                      \
        const float V = __builtin_amdgcn_exp2f(cs);                          \
        const float t4 = 1.0f + Bo_;                                         \
        const float t5 = 1.0f + V;                                           \
        const float r2v = __builtin_amdgcn_rcpf(t4 * t5);                    \
        h = (V - 1.0f) * r2v;                                                \
    }

    // 32 iterations x 2 phases of 8 steps; x buffer role swap (no copies).
    for (int it = 0; it < SEQLEN / (2 * BSTEP); ++it) {
        const int tb = it * 2 * BSTEP;
        {
            const f32x4* v4 = (const f32x4*)(xp + (tb + BSTEP) * INSZ);
#pragma unroll
            for (int i = 0; i < BV; ++i) bufB[i] = v4[i];
#pragma unroll
            for (int ss = 0; ss < BSTEP; ++ss) DO_STEP(bufA, ss)
        }
        {
            int nb = tb + 2 * BSTEP;
            if (nb > SEQLEN - BSTEP) nb = SEQLEN - BSTEP;   // harmless reload
            const f32x4* v4 = (const f32x4*)(xp + nb * INSZ);
#pragma unroll
            for (int i = 0; i < BV; ++i) bufA[i] = v4[i];
#pragma unroll
            for (int ss = 0; ss < BSTEP; ++ss) DO_STEP(bufB, ss)
        }
    }
#undef DO_STEP

    // head: out[seq] = sum_u Wout[u]*h_u + bout (one LDS exchange, per wave)
    const int base = sq * 10;
    const int widx = uvalid ? (base + u) : (40 + (lane & 7));
    hsh[wid][widx] = __builtin_bit_cast(unsigned short, (_Float16)h);
    asm volatile("s_waitcnt lgkmcnt(0)" ::: "memory");
    if (g == 0 && q == 0) {      // lanes 0,4,8,12 -> seqs sq=0..3
        float r = bout[0];
#pragma unroll
        for (int uu = 0; uu < HID; ++uu) {
            const float hv = (float)__builtin_bit_cast(_Float16, hsh[wid][base + uu]);
            r = fmaf(Wout[uu], hv, r);
        }
        out[gwave * 4 + sq] = r;
    }
}

extern "C" void kernel_launch(void* const* d_in, const int* in_sizes, int n_in,
                              void* d_out, int out_size, void* d_ws, size_t ws_size,
                              hipStream_t stream) {
    const float* x    = (const float*)d_in[0];
    const float* Wih  = (const float*)d_in[1];
    const float* Whh  = (const float*)d_in[2];
    const float* bih  = (const float*)d_in[3];
    const float* bhh  = (const float*)d_in[4];
    const float* Wout = (const float*)d_in[5];
    const float* bout = (const float*)d_in[6];
    float* out = (float*)d_out;

    const int threads = 256;
    const int blocks  = (BATCH * 16) / threads;  // 512 blocks = 2048 waves
    lstm_mfma<<<blocks, threads, 0, stream>>>(x, Wih, Whh, bih, bhh, Wout, bout, out);
}